// Round 2
// baseline (175.365 us; speedup 1.0000x reference)
//
#include <hip/hip_runtime.h>
#include <math.h>

// Problem constants
//   B=4, L=4096, D_MODEL=1024, N_HEADS=16, D_HEAD=64, MODES=32
// Rank-64 reassociation:
//   A  = F @ q          [4][64][1024]  (F: 64x4096 DFT rows, bf16 MFMA, atomic K-split)
//   C  = A @ Wv^T       (+ mode-0 bias: C[0] += 4096*bv)  -- fp32 atomic K-split
//   Y  = C * (wr + i wi) interleaved re/im rows
//   Z  = Y @ Wo^T       -- fp32 atomic K-split
//   out= G @ Z + bo     (G: 4096x64 inverse-DFT cols with 1/L,2/L folded; col j=1 zeroed)

typedef __attribute__((ext_vector_type(8))) short bf16x8;
typedef __attribute__((ext_vector_type(8))) unsigned short ushort8;
typedef __attribute__((ext_vector_type(4))) float f32x4;

__device__ __forceinline__ unsigned short f2bf(float x) {
    union { float f; unsigned int u; } c; c.f = x;
    unsigned int u = c.u + 0x7FFFu + ((c.u >> 16) & 1u);   // RNE
    return (unsigned short)(u >> 16);
}

// ---------------------------------------------------------------------------
// init: F[64][4096] bf16, G[4096][64] bf16, zero A/C/Z fp32 accumulators
// ---------------------------------------------------------------------------
__global__ __launch_bounds__(256) void k_init(unsigned short* __restrict__ F,
                                              unsigned short* __restrict__ G,
                                              float* __restrict__ A,
                                              float* __restrict__ C,
                                              float* __restrict__ Z) {
    int idx = blockIdx.x * 256 + threadIdx.x;        // 0..262143
    const float w0 = 1.5339807878856412e-3f;          // 2*pi/4096
    {   // F[j][t]: j=2k -> cos(2pi k t/L), j=2k+1 -> -sin(2pi k t/L)
        int j = idx >> 12, t = idx & 4095, k = j >> 1;
        int r = (k * t) & 4095;
        float s, c; sincosf((float)r * w0, &s, &c);
        F[idx] = f2bf((j & 1) ? -s : c);
    }
    {   // G[t][j]: j=2k -> ck*cos, j=2k+1 -> -ck*sin (0 for k==0), ck = (k?2:1)/L
        int j = idx & 63, k = j >> 1;
        int t = idx >> 6;
        int r = (k * t) & 4095;
        float s, c; sincosf((float)r * w0, &s, &c);
        float ck = (k == 0) ? (1.0f / 4096.0f) : (2.0f / 4096.0f);
        float v = (j & 1) ? ((k == 0) ? 0.0f : -ck * s) : ck * c;
        G[idx] = f2bf(v);
    }
    A[idx] = 0.0f;
    C[idx] = 0.0f;
    Z[idx] = 0.0f;
}

// ---------------------------------------------------------------------------
// K1: A[b][64 j][1024 n] += F[64 j][t-chunk] @ q[b][t-chunk][n-strip]
// LDS-free, barrier-free: q is already in B-operand orientation ([k=t][n]),
// so B-fragments are loaded straight from global (16 lanes x consecutive n
// = coalesced 64B segments), converted to bf16 in-register. F fragments are
// 16B dwordx4 loads (L2-resident). Compiler can pipeline loads across K.
// grid = b(4) x nt(8, N=128) x kp(16, K=256); 256 thr = 4 waves, wave=32 n
// ---------------------------------------------------------------------------
__global__ __launch_bounds__(256) void k_dft_fwd(const float* __restrict__ q,
                                                 const unsigned short* __restrict__ F,
                                                 float* __restrict__ A) {
    int blk = blockIdx.x;
    int kp = blk & 15, nt = (blk >> 4) & 7, b = blk >> 7;
    int tid = threadIdx.x, lane = tid & 63, w = tid >> 6;
    int lm = lane & 15, q4 = lane >> 4;
    int n0 = nt * 128 + w * 32;
    int t0 = kp * 256;
    f32x4 acc[4][2] = {};
    #pragma unroll 2
    for (int ks = 0; ks < 8; ++ks) {
        int tb = t0 + ks * 32 + q4 * 8;
        bf16x8 af[4];
        #pragma unroll
        for (int mt = 0; mt < 4; ++mt)
            af[mt] = *(const bf16x8*)&F[(mt * 16 + lm) * 4096 + tb];
        bf16x8 bq[2];
        #pragma unroll
        for (int ntt = 0; ntt < 2; ++ntt) {
            const float* qp = &q[(size_t)(b * 4096 + tb) * 1024 + n0 + ntt * 16 + lm];
            float f0 = qp[0 * 1024], f1 = qp[1 * 1024], f2 = qp[2 * 1024], f3 = qp[3 * 1024];
            float f4 = qp[4 * 1024], f5 = qp[5 * 1024], f6 = qp[6 * 1024], f7 = qp[7 * 1024];
            union { unsigned int u[4]; bf16x8 v; } cv;
            cv.u[0] = (unsigned)f2bf(f0) | ((unsigned)f2bf(f1) << 16);
            cv.u[1] = (unsigned)f2bf(f2) | ((unsigned)f2bf(f3) << 16);
            cv.u[2] = (unsigned)f2bf(f4) | ((unsigned)f2bf(f5) << 16);
            cv.u[3] = (unsigned)f2bf(f6) | ((unsigned)f2bf(f7) << 16);
            bq[ntt] = cv.v;
        }
        #pragma unroll
        for (int mt = 0; mt < 4; ++mt)
            #pragma unroll
            for (int ntt = 0; ntt < 2; ++ntt)
                acc[mt][ntt] = __builtin_amdgcn_mfma_f32_16x16x32_bf16(
                    af[mt], bq[ntt], acc[mt][ntt], 0, 0, 0);
    }
    #pragma unroll
    for (int mt = 0; mt < 4; ++mt)
        #pragma unroll
        for (int ntt = 0; ntt < 2; ++ntt)
            #pragma unroll
            for (int r = 0; r < 4; ++r) {
                int j = mt * 16 + q4 * 4 + r;
                int n = n0 + ntt * 16 + lm;
                atomicAdd(&A[(b * 64 + j) * 1024 + n], acc[mt][ntt][r]);
            }
}

// ---------------------------------------------------------------------------
// K2/K4: Cout[256 m][1024 n] += Ain[256 m][k-chunk] @ Bmat[1024 n][k-chunk]^T
// grid = mt(4) x nt(8) x kp(8); block 256 thr; Ain fp32 (template 0) or bf16 (1)
// fp32 atomicAdd epilogue (replaces 8MB partial round-trip + reduce kernel)
// ---------------------------------------------------------------------------
template<int ABF16>
__global__ __launch_bounds__(256) void k_gemm_bt(const void* __restrict__ Ain,
                                                 const float* __restrict__ Bmat,
                                                 float* __restrict__ Cout) {
    __shared__ __align__(16) unsigned short At[64 * 40];
    __shared__ __align__(16) unsigned short Wt[128 * 40];
    int blk = blockIdx.x;
    int kp = blk & 7, nt = (blk >> 3) & 7, mt = blk >> 6;
    int m0 = mt * 64, n0 = nt * 128, k0 = kp * 128;
    int tid = threadIdx.x, lane = tid & 63, w = tid >> 6;
    int lm = lane & 15, q4 = lane >> 4;
    int ma = tid >> 2, ka = (tid & 3) * 8;
    int nw = tid >> 1, kw = (tid & 1) * 16;
    f32x4 acc[4][2] = {};
    for (int ks = 0; ks < 4; ++ks) {
        int kb = k0 + ks * 32;
        if (ABF16) {
            ushort8 v = *(const ushort8*)&((const unsigned short*)Ain)[(m0 + ma) * 1024 + kb + ka];
            *(ushort8*)&At[ma * 40 + ka] = v;
        } else {
            const float* Af = (const float*)Ain;
            float4 x0 = *(const float4*)&Af[(m0 + ma) * 1024 + kb + ka];
            float4 x1 = *(const float4*)&Af[(m0 + ma) * 1024 + kb + ka + 4];
            ushort8 v;
            v[0]=f2bf(x0.x); v[1]=f2bf(x0.y); v[2]=f2bf(x0.z); v[3]=f2bf(x0.w);
            v[4]=f2bf(x1.x); v[5]=f2bf(x1.y); v[6]=f2bf(x1.z); v[7]=f2bf(x1.w);
            *(ushort8*)&At[ma * 40 + ka] = v;
        }
        {
            const float4* wp = (const float4*)&Bmat[(n0 + nw) * 1024 + kb + kw];
            float4 x0 = wp[0], x1 = wp[1], x2 = wp[2], x3 = wp[3];
            ushort8 v0, v1;
            v0[0]=f2bf(x0.x); v0[1]=f2bf(x0.y); v0[2]=f2bf(x0.z); v0[3]=f2bf(x0.w);
            v0[4]=f2bf(x1.x); v0[5]=f2bf(x1.y); v0[6]=f2bf(x1.z); v0[7]=f2bf(x1.w);
            v1[0]=f2bf(x2.x); v1[1]=f2bf(x2.y); v1[2]=f2bf(x2.z); v1[3]=f2bf(x2.w);
            v1[4]=f2bf(x3.x); v1[5]=f2bf(x3.y); v1[6]=f2bf(x3.z); v1[7]=f2bf(x3.w);
            *(ushort8*)&Wt[nw * 40 + kw]     = v0;
            *(ushort8*)&Wt[nw * 40 + kw + 8] = v1;
        }
        __syncthreads();
        bf16x8 af[4], bf[2];
        #pragma unroll
        for (int mti = 0; mti < 4; ++mti)
            af[mti] = *(const bf16x8*)&At[(mti * 16 + lm) * 40 + q4 * 8];
        #pragma unroll
        for (int ntt = 0; ntt < 2; ++ntt)
            bf[ntt] = *(const bf16x8*)&Wt[(w * 32 + ntt * 16 + lm) * 40 + q4 * 8];
        #pragma unroll
        for (int mti = 0; mti < 4; ++mti)
            #pragma unroll
            for (int ntt = 0; ntt < 2; ++ntt)
                acc[mti][ntt] = __builtin_amdgcn_mfma_f32_16x16x32_bf16(
                    af[mti], bf[ntt], acc[mti][ntt], 0, 0, 0);
        __syncthreads();
    }
    #pragma unroll
    for (int mti = 0; mti < 4; ++mti)
        #pragma unroll
        for (int ntt = 0; ntt < 2; ++ntt)
            #pragma unroll
            for (int r = 0; r < 4; ++r) {
                int m = m0 + mti * 16 + q4 * 4 + r;
                int n = n0 + w * 32 + ntt * 16 + lm;
                atomicAdd(&Cout[m * 1024 + n], acc[mti][ntt][r]);
            }
}

// ---------------------------------------------------------------------------
// K3: mode-0 bias + complex multiply by w -> Y bf16  (reads fp32 C directly)
// ---------------------------------------------------------------------------
__global__ __launch_bounds__(256) void k_cmul(const float* __restrict__ C,
                                              const float* __restrict__ bv,
                                              const float* __restrict__ wr,
                                              const float* __restrict__ wi,
                                              unsigned short* __restrict__ Y) {
    int idx = blockIdx.x * 256 + threadIdx.x;     // 131072 = 4*32*1024
    int n = idx & 1023, k = (idx >> 10) & 31, b = idx >> 15;
    int rowr = (b * 64 + 2 * k) * 1024 + n;
    int rowi = rowr + 1024;
    float re = C[rowr];
    float im = C[rowi];
    if (k == 0) re += 4096.0f * bv[n];            // bias only feeds the DC bin
    int h = n >> 6, dh = n & 63;
    float a = wr[(h * 32 + k) * 64 + dh];
    float c = wi[(h * 32 + k) * 64 + dh];
    Y[rowr] = f2bf(re * a - im * c);
    Y[rowi] = f2bf(re * c + im * a);
}

// ---------------------------------------------------------------------------
// K5: out[b][t][n] = G[t][64] @ Z[b][64][n] + bo[n]   (Z fp32, fp32 out 64 MB)
// grid = b(4) x ttile(32) x ntile(8); block 256 thr = 4 waves of 64x64
// ---------------------------------------------------------------------------
__global__ __launch_bounds__(256) void k_dft_inv(const unsigned short* __restrict__ G,
                                                 const float* __restrict__ Zf,
                                                 const float* __restrict__ bo,
                                                 float* __restrict__ out) {
    __shared__ __align__(16) unsigned short Gt[128 * 72];  // [t][j] pad->72
    __shared__ __align__(16) unsigned short ZT[128 * 72];  // [n][j] pad->72
    int blk = blockIdx.x;
    int nt = blk & 7, tt = (blk >> 3) & 31, b = blk >> 8;
    int n0 = nt * 128, t0 = tt * 128;
    int tid = threadIdx.x, lane = tid & 63, w = tid >> 6;
    int lm = lane & 15, q4 = lane >> 4;
    // stage G tile [128 t][64 j] (contiguous rows)
    {
        int ttl = tid >> 1, jj = (tid & 1) * 32;
        #pragma unroll
        for (int i = 0; i < 4; ++i) {
            ushort8 v = *(const ushort8*)&G[(t0 + ttl) * 64 + jj + i * 8];
            *(ushort8*)&Gt[ttl * 72 + jj + i * 8] = v;
        }
    }
    // stage Z^T tile [128 n][64 j]: read fp32 row pairs, pack (j,j+1) as u32
    {
        int jp = tid & 31, hi = tid >> 5;
        int j = jp * 2, nn0 = hi * 16;
        const float* r0 = &Zf[(b * 64 + j) * 1024 + n0 + nn0];
        const float* r1 = r0 + 1024;
        float za[16], zb[16];
        #pragma unroll
        for (int i = 0; i < 4; ++i) {
            float4 va = ((const float4*)r0)[i];
            float4 vb = ((const float4*)r1)[i];
            za[4*i+0] = va.x; za[4*i+1] = va.y; za[4*i+2] = va.z; za[4*i+3] = va.w;
            zb[4*i+0] = vb.x; zb[4*i+1] = vb.y; zb[4*i+2] = vb.z; zb[4*i+3] = vb.w;
        }
        #pragma unroll
        for (int i = 0; i < 16; ++i) {
            unsigned int v = (unsigned)f2bf(za[i]) | ((unsigned)f2bf(zb[i]) << 16);
            *(unsigned int*)&ZT[(nn0 + i) * 72 + j] = v;
        }
    }
    __syncthreads();
    int wt0 = (w >> 1) * 64, wn0 = (w & 1) * 64;
    f32x4 acc[4][4] = {};
    #pragma unroll
    for (int ks = 0; ks < 2; ++ks) {
        bf16x8 af[4], bf[4];
        #pragma unroll
        for (int mt = 0; mt < 4; ++mt)
            af[mt] = *(const bf16x8*)&Gt[(wt0 + mt * 16 + lm) * 72 + ks * 32 + q4 * 8];
        #pragma unroll
        for (int ntt = 0; ntt < 4; ++ntt)
            bf[ntt] = *(const bf16x8*)&ZT[(wn0 + ntt * 16 + lm) * 72 + ks * 32 + q4 * 8];
        #pragma unroll
        for (int mt = 0; mt < 4; ++mt)
            #pragma unroll
            for (int ntt = 0; ntt < 4; ++ntt)
                acc[mt][ntt] = __builtin_amdgcn_mfma_f32_16x16x32_bf16(
                    af[mt], bf[ntt], acc[mt][ntt], 0, 0, 0);
    }
    #pragma unroll
    for (int ntt = 0; ntt < 4; ++ntt) {
        int n = n0 + wn0 + ntt * 16 + lm;
        float bov = bo[n];
        #pragma unroll
        for (int mt = 0; mt < 4; ++mt)
            #pragma unroll
            for (int r = 0; r < 4; ++r) {
                int t = t0 + wt0 + mt * 16 + q4 * 4 + r;
                out[(size_t)(b * 4096 + t) * 1024 + n] = acc[mt][ntt][r] + bov;
            }
    }
}

// ---------------------------------------------------------------------------
extern "C" void kernel_launch(void* const* d_in, const int* in_sizes, int n_in,
                              void* d_out, int out_size, void* d_ws, size_t ws_size,
                              hipStream_t stream) {
    const float* q  = (const float*)d_in[0];
    const float* Wv = (const float*)d_in[1];
    const float* bv = (const float*)d_in[2];
    const float* Wo = (const float*)d_in[3];
    const float* bo = (const float*)d_in[4];
    const float* wr = (const float*)d_in[5];
    const float* wi = (const float*)d_in[6];
    float* out = (float*)d_out;

    char* ws = (char*)d_ws;
    unsigned short* F  = (unsigned short*)(ws);                           // 512 KB
    unsigned short* G  = (unsigned short*)(ws + (512 << 10));             // 512 KB
    float*          A  = (float*)(ws + (1u << 20));                       // 1 MB fp32
    float*          C  = (float*)(ws + (2u << 20));                       // 1 MB fp32
    float*          Z  = (float*)(ws + (3u << 20));                       // 1 MB fp32
    unsigned short* Y  = (unsigned short*)(ws + (4u << 20));              // 512 KB

    hipLaunchKernelGGL(k_init,         dim3(1024), dim3(256), 0, stream, F, G, A, C, Z);
    hipLaunchKernelGGL(k_dft_fwd,      dim3(512),  dim3(256), 0, stream, q, F, A);
    hipLaunchKernelGGL((k_gemm_bt<0>), dim3(256),  dim3(256), 0, stream, (const void*)A, Wv, C);
    hipLaunchKernelGGL(k_cmul,         dim3(512),  dim3(256), 0, stream, C, bv, wr, wi, Y);
    hipLaunchKernelGGL((k_gemm_bt<1>), dim3(256),  dim3(256), 0, stream, (const void*)Y, Wo, Z);
    hipLaunchKernelGGL(k_dft_inv,      dim3(1024), dim3(256), 0, stream, G, Z, bo, out);
}